// Round 1
// baseline (83.180 us; speedup 1.0000x reference)
//
#include <hip/hip_runtime.h>

#define H 4096
#define THREADS 256
#define ROWS 4
#define CHUNKS 4   // H / (THREADS * 4)

__device__ __forceinline__ float dot4(float4 a, float4 b) {
    return a.x * b.x + a.y * b.y + a.z * b.z + a.w * b.w;
}

// Tiny pre-kernel: C[r'][r] = sum_d A_v[r'][d] * B_q[d][r]   (4x4)
__global__ void __launch_bounds__(THREADS) compute_C_kernel(
    const float* __restrict__ A_v, const float* __restrict__ B_q,
    float* __restrict__ C)
{
    const int tid = threadIdx.x;
    float acc[4][4];
#pragma unroll
    for (int i = 0; i < 4; ++i)
#pragma unroll
        for (int j = 0; j < 4; ++j) acc[i][j] = 0.f;

#pragma unroll
    for (int c = 0; c < CHUNKS; ++c) {
        const int d0 = c * (THREADS * 4) + tid * 4;
        float avf[4][4], bqf[4][4];
#pragma unroll
        for (int r = 0; r < 4; ++r) {
            float4 t = *reinterpret_cast<const float4*>(A_v + (size_t)r * H + d0);
            avf[r][0] = t.x; avf[r][1] = t.y; avf[r][2] = t.z; avf[r][3] = t.w;
        }
#pragma unroll
        for (int i = 0; i < 4; ++i) {
            float4 t = *reinterpret_cast<const float4*>(B_q + (size_t)(d0 + i) * 4);
            bqf[i][0] = t.x; bqf[i][1] = t.y; bqf[i][2] = t.z; bqf[i][3] = t.w;
        }
#pragma unroll
        for (int i = 0; i < 4; ++i)
#pragma unroll
            for (int rp = 0; rp < 4; ++rp)
#pragma unroll
                for (int r = 0; r < 4; ++r)
                    acc[rp][r] += avf[rp][i] * bqf[i][r];
    }

    const int lane = tid & 63, wave = tid >> 6;
    __shared__ float red[4][16];
#pragma unroll
    for (int rp = 0; rp < 4; ++rp)
#pragma unroll
        for (int r = 0; r < 4; ++r) {
            float v = acc[rp][r];
#pragma unroll
            for (int off = 32; off; off >>= 1) v += __shfl_down(v, off, 64);
            if (lane == 0) red[wave][rp * 4 + r] = v;
        }
    __syncthreads();
    if (tid < 16) C[tid] = red[0][tid] + red[1][tid] + red[2][tid] + red[3][tid];
}

// Fused: each block owns ROWS rows. Phase 1: low_q / lowx_v reductions
// (x kept in registers). Phase 2: out = 2*(x + lq.Bq[d] + lv.Bv[d]).
__global__ void __launch_bounds__(THREADS) lora_fused_kernel(
    const float* __restrict__ x,
    const float* __restrict__ A_q, const float* __restrict__ B_q,
    const float* __restrict__ A_v, const float* __restrict__ B_v,
    const float* __restrict__ C,
    float* __restrict__ out)
{
    const int tid = threadIdx.x;
    const size_t row0 = (size_t)blockIdx.x * ROWS;
    const float* xbase = x + row0 * H;

    float4 xr[ROWS][CHUNKS];
    float accq[ROWS][4], accv[ROWS][4];
#pragma unroll
    for (int m = 0; m < ROWS; ++m)
#pragma unroll
        for (int r = 0; r < 4; ++r) { accq[m][r] = 0.f; accv[m][r] = 0.f; }

#pragma unroll
    for (int c = 0; c < CHUNKS; ++c) {
        const int d0 = c * (THREADS * 4) + tid * 4;
        float4 aq[4], av[4];
#pragma unroll
        for (int r = 0; r < 4; ++r) {
            aq[r] = *reinterpret_cast<const float4*>(A_q + (size_t)r * H + d0);
            av[r] = *reinterpret_cast<const float4*>(A_v + (size_t)r * H + d0);
        }
#pragma unroll
        for (int m = 0; m < ROWS; ++m) {
            float4 xv = *reinterpret_cast<const float4*>(xbase + (size_t)m * H + d0);
            xr[m][c] = xv;
#pragma unroll
            for (int r = 0; r < 4; ++r) {
                accq[m][r] += dot4(xv, aq[r]);
                accv[m][r] += dot4(xv, av[r]);
            }
        }
    }

    // Block-wide reduce of 8 values per row.
    const int lane = tid & 63, wave = tid >> 6;
    __shared__ float red[ROWS][4][8];   // [row][wave][val]
#pragma unroll
    for (int m = 0; m < ROWS; ++m)
#pragma unroll
        for (int v = 0; v < 8; ++v) {
            float s = (v < 4) ? accq[m][v] : accv[m][v - 4];
#pragma unroll
            for (int off = 32; off; off >>= 1) s += __shfl_down(s, off, 64);
            if (lane == 0) red[m][wave][v] = s;
        }
    __syncthreads();

    float cm[16];
#pragma unroll
    for (int i = 0; i < 16; ++i) cm[i] = C[i];

    float lq[ROWS][4], lv[ROWS][4];
#pragma unroll
    for (int m = 0; m < ROWS; ++m) {
        float lvx[4];
#pragma unroll
        for (int r = 0; r < 4; ++r) {
            lq[m][r] = red[m][0][r] + red[m][1][r] + red[m][2][r] + red[m][3][r];
            lvx[r]   = red[m][0][4 + r] + red[m][1][4 + r] + red[m][2][4 + r] + red[m][3][4 + r];
        }
#pragma unroll
        for (int rp = 0; rp < 4; ++rp) {
            float s = lvx[rp];
#pragma unroll
            for (int r = 0; r < 4; ++r) s += 2.f * lq[m][r] * cm[rp * 4 + r];
            lv[m][rp] = s;
        }
    }

    // Phase 2: out = 2*(x + lq.Bq[d] + lv.Bv[d])   (x from registers)
#pragma unroll
    for (int c = 0; c < CHUNKS; ++c) {
        const int d0 = c * (THREADS * 4) + tid * 4;
        float bqf[4][4], bvf[4][4];
#pragma unroll
        for (int i = 0; i < 4; ++i) {
            float4 t = *reinterpret_cast<const float4*>(B_q + (size_t)(d0 + i) * 4);
            bqf[i][0] = t.x; bqf[i][1] = t.y; bqf[i][2] = t.z; bqf[i][3] = t.w;
            float4 u = *reinterpret_cast<const float4*>(B_v + (size_t)(d0 + i) * 4);
            bvf[i][0] = u.x; bvf[i][1] = u.y; bvf[i][2] = u.z; bvf[i][3] = u.w;
        }
#pragma unroll
        for (int m = 0; m < ROWS; ++m) {
            float4 xv = xr[m][c];
            float xs[4] = {xv.x, xv.y, xv.z, xv.w};
            float o[4];
#pragma unroll
            for (int i = 0; i < 4; ++i) {
                float dq = lq[m][0] * bqf[i][0] + lq[m][1] * bqf[i][1]
                         + lq[m][2] * bqf[i][2] + lq[m][3] * bqf[i][3];
                float dv = lv[m][0] * bvf[i][0] + lv[m][1] * bvf[i][1]
                         + lv[m][2] * bvf[i][2] + lv[m][3] * bvf[i][3];
                o[i] = 2.f * (xs[i] + dq + dv);
            }
            float4 ov = make_float4(o[0], o[1], o[2], o[3]);
            *reinterpret_cast<float4*>(out + (row0 + m) * H + d0) = ov;
        }
    }
}

extern "C" void kernel_launch(void* const* d_in, const int* in_sizes, int n_in,
                              void* d_out, int out_size, void* d_ws, size_t ws_size,
                              hipStream_t stream) {
    const float* x   = (const float*)d_in[0];
    const float* A_q = (const float*)d_in[1];
    const float* B_q = (const float*)d_in[2];
    const float* A_v = (const float*)d_in[3];
    const float* B_v = (const float*)d_in[4];
    float* out = (float*)d_out;
    float* C   = (float*)d_ws;          // 16 floats

    const int rows = in_sizes[0] / H;   // B*S = 8192

    compute_C_kernel<<<1, THREADS, 0, stream>>>(A_v, B_q, C);
    lora_fused_kernel<<<rows / ROWS, THREADS, 0, stream>>>(
        x, A_q, B_q, A_v, B_v, C, out);
}